// Round 2
// baseline (246.715 us; speedup 1.0000x reference)
//
#include <hip/hip_runtime.h>

#define BATCH 256
#define CHAN  3
#define HIN   256
#define WIN   256
#define HOUT  64
#define WOUT  64

// One thread computes 4 consecutive output pixels (float4 store) for all 3
// channels. y-coords/weights shared across the 4 pixels; x-corner gathers are
// per-pixel (span depends on runtime sx, cannot be statically vectorized).
__global__ __launch_bounds__(256) void st_kernel(
    const float* __restrict__ x,
    const float* __restrict__ zw,
    const int*   __restrict__ inv_p,
    float*       __restrict__ out)
{
    const int tid = blockIdx.x * 256 + threadIdx.x;   // b*1024 + oy*16 + qx
    const int qx = tid & 15;          // quad index: ox = 4*qx .. 4*qx+3
    const int oy = (tid >> 4) & 63;
    const int b  = tid >> 10;

    // per-batch transform params (uniform within a block's quarter-batch)
    const float z0 = zw[b * 4 + 0];
    const float z1 = zw[b * 4 + 1];
    const float z2 = zw[b * 4 + 2];
    const float z3 = zw[b * 4 + 3];

    float sx, sy, tx, ty;
    if (inv_p[0]) {
        const float s0 = z0 + 1e-6f, s1 = z1 + 1e-6f;
        sx = 1.0f / s0;  sy = 1.0f / s1;
        tx = -z2 / s0;   ty = -z3 / s1;
    } else {
        sx = z0; sy = z1; tx = z2; ty = z3;
    }

    // ---- y (shared across the 4 pixels) ----
    const float ys = (2.0f * (float)oy + 1.0f) / (float)HOUT - 1.0f;
    const float v  = sy * ys + ty;
    const float iy = ((v + 1.0f) * (float)HIN - 1.0f) * 0.5f;
    const float fy0 = floorf(iy);
    const int y0 = (int)fy0, y1 = y0 + 1;
    const float wy1 = iy - fy0, wy0 = 1.0f - wy1;
    const bool vy0 = (y0 >= 0) && (y0 < HIN);
    const bool vy1 = (y1 >= 0) && (y1 < HIN);
    const int yc0 = min(max(y0, 0), HIN - 1);
    const int yc1 = min(max(y1, 0), HIN - 1);

    // ---- x (per pixel) ----
    int   ox0[4], ox1[4];
    float w00[4], w01[4], w10[4], w11[4];
#pragma unroll
    for (int j = 0; j < 4; ++j) {
        const int ox = qx * 4 + j;
        const float xs = (2.0f * (float)ox + 1.0f) / (float)WOUT - 1.0f;
        const float u  = sx * xs + tx;
        const float ix = ((u + 1.0f) * (float)WIN - 1.0f) * 0.5f;
        const float fx0 = floorf(ix);
        const int x0 = (int)fx0, x1 = x0 + 1;
        const float wx1 = ix - fx0, wx0 = 1.0f - wx1;
        const bool vx0 = (x0 >= 0) && (x0 < WIN);
        const bool vx1 = (x1 >= 0) && (x1 < WIN);
        // zeros padding == zero the weight of any invalid corner
        w00[j] = (vy0 && vx0) ? (wy0 * wx0) : 0.0f;
        w01[j] = (vy0 && vx1) ? (wy0 * wx1) : 0.0f;
        w10[j] = (vy1 && vx0) ? (wy1 * wx0) : 0.0f;
        w11[j] = (vy1 && vx1) ? (wy1 * wx1) : 0.0f;
        ox0[j] = min(max(x0, 0), WIN - 1);
        ox1[j] = min(max(x1, 0), WIN - 1);
    }

    const float* __restrict__ xb = x + (size_t)b * (CHAN * HIN * WIN);
    float* __restrict__ ob = out + (size_t)b * (CHAN * HOUT * WOUT)
                                 + oy * WOUT + qx * 4;

#pragma unroll
    for (int c = 0; c < CHAN; ++c) {
        const float* __restrict__ r0 = xb + c * (HIN * WIN) + yc0 * WIN;
        const float* __restrict__ r1 = xb + c * (HIN * WIN) + yc1 * WIN;
        float4 res;
        float* rp = (float*)&res;
#pragma unroll
        for (int j = 0; j < 4; ++j) {
            rp[j] = r0[ox0[j]] * w00[j] + r0[ox1[j]] * w01[j]
                  + r1[ox0[j]] * w10[j] + r1[ox1[j]] * w11[j];
        }
        *(float4*)(ob + c * (HOUT * WOUT)) = res;
    }
}

extern "C" void kernel_launch(void* const* d_in, const int* in_sizes, int n_in,
                              void* d_out, int out_size, void* d_ws, size_t ws_size,
                              hipStream_t stream) {
    const float* x   = (const float*)d_in[0];
    const float* zw  = (const float*)d_in[1];
    const int*   inv = (const int*)d_in[2];
    float* out = (float*)d_out;

    const int total  = BATCH * HOUT * (WOUT / 4);  // one thread per 4 pixels
    const int blocks = total / 256;                // 1024
    st_kernel<<<blocks, 256, 0, stream>>>(x, zw, inv, out);
}